// Round 4
// baseline (143.523 us; speedup 1.0000x reference)
//
#include <hip/hip_runtime.h>

// PlaceCellNetwork — 50 fixed-point Jacobi iterations, per-row independent.
//
// R4: coefficient matrix in SGPRs via v_readfirstlane.
//
// R3 post-mortem: VGPR_Count=72 proved the compiler rematerialized the
// Gn[k][j] = (-DT*rd[k])*M[k][j] products inside the loop (~100 extra v_mul
// per iteration = 2x instruction bloat, matching 68 us vs the 35 us fp32-pipe
// floor). Fix: Gn is wave-uniform, so force it into SGPRs with
// v_readfirstlane (exact — all lanes identical). Every inner op is then one
// v_fma_f32 with SGPR src0 (legal: <=1 SGPR read per VALU instr) — nothing
// left to rematerialize, VGPR pressure collapses.
//
// SGPR budget: 90 off-diag coefficients + loop counter + out-ptr + misc ~ 96
// of ~102 architected. Diagonal A[j] and rd[j] deliberately stay in VGPRs to
// stay under the ceiling (VGPRs are plentiful at ~50 live).
//
// Iteration (z-space, algebraically identical to reference; Y_j = rd_j*z_j):
//   z_j <- max( A_j*z_j + c_j + sum_{k!=j} Gn[k][j]*z_k , 0 )
//   A_j = (1-dt)*rd_j,  rd_j = 1/(lbd2+M_jj),  Gn[k][j] = -dt*rd_k*M_kj
//   c_j = dt*(Wx_j - b_j) - lbd1
//
// fp32-pipe roofline: 500k rows x 50 iters x 110 wave64-VALU ops
//   = 7813 waves x 5500 instr x 2 cyc / 1024 SIMDs ~ 84k cyc ~ 35 us.

constexpr int IN_DIM  = 5;
constexpr int OUT_DIM = 10;
constexpr int ITERS   = 50;

__device__ __forceinline__ float rfl(float v) {
    // wave-uniform value -> SGPR (exact: all lanes identical)
    return __int_as_float(__builtin_amdgcn_readfirstlane(__float_as_int(v)));
}

__global__ __launch_bounds__(256, 1) void pcn_kernel(
    const float* __restrict__ X,    // [n, 5]
    const float* __restrict__ W,    // [10, 5]
    const float* __restrict__ Mg,   // [10, 10]
    const float* __restrict__ b,    // [10]
    float* __restrict__ out,        // [n, 10]
    int n)
{
    const float DT = 0.05f, LBD1 = 0.005f, LBD2 = 0.005f;

    int i = blockIdx.x * blockDim.x + threadIdx.x;
    if (i >= n) return;

    // ---- uniform tables (prologue, once) ----
    float rd[OUT_DIM], A[OUT_DIM];
#pragma unroll
    for (int j = 0; j < OUT_DIM; ++j) {
        rd[j] = 1.0f / (LBD2 + Mg[j * OUT_DIM + j]);   // precise div, once
        A[j]  = (1.0f - DT) * rd[j];                   // stays in VGPR
    }
    // Off-diagonal coefficients -> SGPRs. Gn[k][j] only read for k != j.
    float Gn[OUT_DIM][OUT_DIM];
#pragma unroll
    for (int k = 0; k < OUT_DIM; ++k) {
        float f = -DT * rd[k];
#pragma unroll
        for (int j = 0; j < OUT_DIM; ++j) {
            Gn[k][j] = (j != k) ? rfl(f * Mg[k * OUT_DIM + j]) : 0.0f;
        }
    }

    // ---- per-row constant c ----
    float x[IN_DIM];
#pragma unroll
    for (int d = 0; d < IN_DIM; ++d) x[d] = X[(size_t)i * IN_DIM + d];
    float c[OUT_DIM];
#pragma unroll
    for (int j = 0; j < OUT_DIM; ++j) {
        float s = -b[j];
#pragma unroll
        for (int d = 0; d < IN_DIM; ++d)
            s = fmaf(x[d], W[j * IN_DIM + d], s);
        c[j] = fmaf(DT, s, -LBD1);
    }

    // ---- 50 iterations, ping-pong; 11 VALU per output per iteration ----
    float z[OUT_DIM], zn[OUT_DIM];
#pragma unroll
    for (int j = 0; j < OUT_DIM; ++j) z[j] = 0.0f;

    auto step = [&](const float* zi, float* zo) {
#pragma unroll
        for (int j = 0; j < OUT_DIM; ++j) {
            float s = fmaf(A[j], zi[j], c[j]);        // VGPRxVGPR+VGPR
#pragma unroll
            for (int k = 0; k < OUT_DIM; ++k)
                if (k != j)
                    s = fmaf(Gn[k][j], zi[k], s);     // SGPRxVGPR+VGPR
            zo[j] = fmaxf(s, 0.0f);
        }
    };

#pragma unroll 1
    for (int it = 0; it < ITERS / 2; ++it) {   // ~1.8 KB loop body: I$-friendly
        step(z, zn);
        step(zn, z);
    }

    // ---- epilogue: Y = rd .* z ----
#pragma unroll
    for (int j = 0; j < OUT_DIM; ++j)
        out[(size_t)i * OUT_DIM + j] = rd[j] * z[j];
}

extern "C" void kernel_launch(void* const* d_in, const int* in_sizes, int n_in,
                              void* d_out, int out_size, void* d_ws, size_t ws_size,
                              hipStream_t stream) {
    const float* X = (const float*)d_in[0];
    const float* W = (const float*)d_in[1];
    const float* M = (const float*)d_in[2];
    const float* b = (const float*)d_in[3];
    float* out = (float*)d_out;

    int n = in_sizes[0] / IN_DIM;   // 500000 rows
    int block = 256;
    int grid = (n + block - 1) / block;
    pcn_kernel<<<grid, block, 0, stream>>>(X, W, M, b, out, n);
}

// Round 5
// 122.271 us; speedup vs baseline: 1.1738x; 1.1738x over previous
//
#include <hip/hip_runtime.h>

// PlaceCellNetwork — 50 fixed-point Jacobi iterations, per-row independent.
//
// R5: pin the uniform coefficient table in VGPRs with empty inline-asm.
//
// History: R3 (VGPR table) hit 68 us, 2x above the 35 us fp32-pipe floor,
// because regalloc REMATERIALIZED Gn[k][j] = f_k*M_kj inside the loop
// (VGPR_Count=72 proved the table wasn't resident; ~100 extra v_mul/iter).
// R4 (SGPR table via readfirstlane) regressed to 86 us: 90 values don't fit
// the ~100-SGPR architected budget, so the scalarization spilled into the
// loop. Fix: compute each coefficient once, then pass it through an empty
// asm "+v" constraint — an asm def cannot be rematerialized, so the value
// must stay VGPR-resident. ~150 live VGPRs -> 3 waves/SIMD, plenty (ILP=10).
//
// Iteration (z-space, algebraically identical to reference; Y_j = rd_j*z_j):
//   z_j <- max( A_j*z_j + c_j + sum_{k!=j} Gn[k][j]*z_k , 0 )
//   A_j = (1-dt)*rd_j,  rd_j = 1/(lbd2+M_jj),  Gn[k][j] = -dt*rd_k*M_kj
//   c_j = dt*(Wx_j - b_j) - lbd1
//
// fp32-pipe roofline: 7813 waves x 5500 instr x 2 cyc / 1024 SIMDs
//   ~ 84k cyc ~ 35 us. Target this round: 38-45 us rocprof.

constexpr int IN_DIM  = 5;
constexpr int OUT_DIM = 10;
constexpr int ITERS   = 50;

// Force v into a VGPR and make its def opaque to remat/CSE.
__device__ __forceinline__ void pin(float& v) { asm("" : "+v"(v)); }

__global__ __launch_bounds__(256, 1) void pcn_kernel(
    const float* __restrict__ X,    // [n, 5]
    const float* __restrict__ W,    // [10, 5]
    const float* __restrict__ Mg,   // [10, 10]
    const float* __restrict__ b,    // [10]
    float* __restrict__ out,        // [n, 10]
    int n)
{
    const float DT = 0.05f, LBD1 = 0.005f, LBD2 = 0.005f;

    int i = blockIdx.x * blockDim.x + threadIdx.x;
    if (i >= n) return;

    // ---- uniform tables (prologue, once), pinned into VGPRs ----
    float rd[OUT_DIM], A[OUT_DIM];
#pragma unroll
    for (int j = 0; j < OUT_DIM; ++j) {
        rd[j] = 1.0f / (LBD2 + Mg[j * OUT_DIM + j]);
        A[j]  = (1.0f - DT) * rd[j];
        pin(A[j]);
        pin(rd[j]);                     // live until epilogue; keep resident
    }
    float Gn[OUT_DIM][OUT_DIM];         // Gn[k][j] = -DT*rd[k]*M[k][j], k!=j
#pragma unroll
    for (int k = 0; k < OUT_DIM; ++k) {
        float f = -DT * rd[k];
#pragma unroll
        for (int j = 0; j < OUT_DIM; ++j) {
            if (j != k) {
                Gn[k][j] = f * Mg[k * OUT_DIM + j];
                pin(Gn[k][j]);
            } else {
                Gn[k][j] = 0.0f;        // never read
            }
        }
    }

    // ---- per-row constant c (from per-lane loads; not remattable) ----
    float x[IN_DIM];
#pragma unroll
    for (int d = 0; d < IN_DIM; ++d) x[d] = X[(size_t)i * IN_DIM + d];
    float c[OUT_DIM];
#pragma unroll
    for (int j = 0; j < OUT_DIM; ++j) {
        float s = -b[j];
#pragma unroll
        for (int d = 0; d < IN_DIM; ++d)
            s = fmaf(x[d], W[j * IN_DIM + d], s);
        c[j] = fmaf(DT, s, -LBD1);
    }

    // ---- 50 iterations, ping-pong; 11 VALU per output per iteration ----
    float z[OUT_DIM], zn[OUT_DIM];
#pragma unroll
    for (int j = 0; j < OUT_DIM; ++j) z[j] = 0.0f;

    auto step = [&](const float* zi, float* zo) {
#pragma unroll
        for (int j = 0; j < OUT_DIM; ++j) {
            float s = fmaf(A[j], zi[j], c[j]);
#pragma unroll
            for (int k = 0; k < OUT_DIM; ++k)
                if (k != j)
                    s = fmaf(Gn[k][j], zi[k], s);   // all-VGPR fma
            zo[j] = fmaxf(s, 0.0f);
        }
    };

#pragma unroll 1
    for (int it = 0; it < ITERS / 2; ++it) {
        step(z, zn);
        step(zn, z);
    }

    // ---- epilogue: Y = rd .* z, contiguous 40B/row store ----
#pragma unroll
    for (int j = 0; j < OUT_DIM; ++j)
        out[(size_t)i * OUT_DIM + j] = rd[j] * z[j];
}

extern "C" void kernel_launch(void* const* d_in, const int* in_sizes, int n_in,
                              void* d_out, int out_size, void* d_ws, size_t ws_size,
                              hipStream_t stream) {
    const float* X = (const float*)d_in[0];
    const float* W = (const float*)d_in[1];
    const float* M = (const float*)d_in[2];
    const float* b = (const float*)d_in[3];
    float* out = (float*)d_out;

    int n = in_sizes[0] / IN_DIM;   // 500000 rows
    int block = 256;
    int grid = (n + block - 1) / block;
    pcn_kernel<<<grid, block, 0, stream>>>(X, W, M, b, out, n);
}